// Round 11
// baseline (254.523 us; speedup 1.0000x reference)
//
#include <hip/hip_runtime.h>
#include <hip/hip_bf16.h>
#include <math.h>

#define BATCH 4
#define SEQ   2048
#define DM    512
#define NH    8
#define DK    64
#define FF    2048
#define BT    (BATCH * SEQ)   // 8192

// q pre-scale: 0.125 * log2(e)  -> softmax uses exp2 directly
#define SCALE_Q 0.18033688011112042f

typedef short bf16x8 __attribute__((ext_vector_type(8)));
typedef float f32x4  __attribute__((ext_vector_type(4)));

static __device__ inline short f2bf(float f) {
  union { float f; unsigned u; } v; v.f = f;
  unsigned r = (v.u + 0x7fffu + ((v.u >> 16) & 1u)) >> 16;
  return (short)r;
}

// async 16B global->LDS (gfx950). LDS dest = wave-uniform base + lane*16.
static __device__ __forceinline__ void gload16(const short* g, short* l) {
  __builtin_amdgcn_global_load_lds(
      (const __attribute__((address_space(1))) void*)g,
      (__attribute__((address_space(3))) void*)l, 16, 0, 0);
}

// Bijective XCD-chunk swizzle: XCD c owns logical ids [c*nwg/8, (c+1)*nwg/8).
// Requires nwg % 8 == 0 (all our grids). Consecutive logical ids keep x
// fastest -> blocks sharing an A-row-panel land on the SAME XCD's L2.
static __device__ __forceinline__ void xcd_swizzle(int& bx, int& by) {
  int gx = gridDim.x;
  int nwg = gx * gridDim.y;
  int id = blockIdx.x + gx * blockIdx.y;
  int nid = (id & 7) * (nwg >> 3) + (id >> 3);
  bx = nid % gx;
  by = nid / gx;
}

// ---------------------------------------------------------------------------
// LayerNorm: one block per row of 512, fp32 in -> bf16 out
// ---------------------------------------------------------------------------
__global__ __launch_bounds__(256) void ln_kernel(
    const float* __restrict__ x, const float* __restrict__ gamma,
    const float* __restrict__ beta, short* __restrict__ out) {
  int row = blockIdx.x;
  const float* xr = x + (size_t)row * DM;
  int t = threadIdx.x;
  float v0 = xr[t], v1 = xr[t + 256];
  float s = v0 + v1;
  float sq = v0 * v0 + v1 * v1;
  for (int off = 32; off; off >>= 1) {
    s  += __shfl_xor(s, off);
    sq += __shfl_xor(sq, off);
  }
  __shared__ float ssum[4], ssq[4];
  int wave = t >> 6, lane = t & 63;
  if (lane == 0) { ssum[wave] = s; ssq[wave] = sq; }
  __syncthreads();
  if (t == 0) {
    float S = ssum[0] + ssum[1] + ssum[2] + ssum[3];
    float Q = ssq[0] + ssq[1] + ssq[2] + ssq[3];
    float mu = S * (1.0f / DM);
    float var = Q * (1.0f / DM) - mu * mu;
    ssum[0] = mu;
    ssq[0] = rsqrtf(var + 1e-5f);
  }
  __syncthreads();
  float mu = ssum[0], rstd = ssq[0];
  short* orow = out + (size_t)row * DM;
  orow[t]       = f2bf((v0 - mu) * rstd * gamma[t]       + beta[t]);
  orow[t + 256] = f2bf((v1 - mu) * rstd * gamma[t + 256] + beta[t + 256]);
}

// ---------------------------------------------------------------------------
// Weight convert+transpose fp32 [R][C] -> bf16 [C][R]. Flat 768-block grid.
// ---------------------------------------------------------------------------
__global__ __launch_bounds__(256) void wconv_kernel(
    const float* Wq, const float* Wk, const float* Wv,
    const float* Wp, const float* W1, const float* W2,
    short* wqkv, short* wpt, short* w1t, short* w2t) {
  int id = blockIdx.x;
  const float* src; short* dst; int R, C, tx, ty;
  if (id < 192) {                      // 24 sub-matrices of 512x64, 8 blocks each
    int z = id >> 3;
    int m = z >> 3, hh = z & 7;
    const float* s0 = (m == 0) ? Wq : (m == 1) ? Wk : Wv;
    src = s0 + (size_t)hh * 512 * 64;
    dst = wqkv + ((size_t)(m * 512 + hh * 64)) * 512;
    R = 512; C = 64; tx = 0; ty = id & 7;
  } else if (id < 256) {               // Wp 512x512: 64 blocks
    int w = id - 192; src = Wp; dst = wpt; R = 512; C = 512;
    tx = w & 7; ty = w >> 3;
  } else if (id < 512) {               // W1 512x2048: 256 blocks
    int w = id - 256; src = W1; dst = w1t; R = 512; C = 2048;
    tx = w & 31; ty = w >> 5;
  } else {                             // W2 2048x512: 256 blocks
    int w = id - 512; src = W2; dst = w2t; R = 2048; C = 512;
    tx = w & 7; ty = w >> 3;
  }
  __shared__ float Ts[64][68];
  int t = threadIdx.x;
  int r = t >> 2, c0 = (t & 3) * 16;
  const float* sp = src + (size_t)(ty * 64 + r) * C + tx * 64 + c0;
#pragma unroll
  for (int i = 0; i < 16; i += 4) {
    float4 v = *(const float4*)(sp + i);
    Ts[c0 + i + 0][r] = v.x; Ts[c0 + i + 1][r] = v.y;
    Ts[c0 + i + 2][r] = v.z; Ts[c0 + i + 3][r] = v.w;
  }
  __syncthreads();
  short* dp = dst + (size_t)(tx * 64 + r) * R + ty * 64 + c0;
  short tmp[16];
#pragma unroll
  for (int i = 0; i < 16; ++i) tmp[i] = f2bf(Ts[r][c0 + i]);
  *(int4*)(dp)     = *(int4*)&tmp[0];
  *(int4*)(dp + 8) = *(int4*)&tmp[8];
}

// ---------------------------------------------------------------------------
// GEMM core (R8): BK=32, double-buffered async staging, operand-swapped
// MFMA so each lane holds 4 consecutive N-columns -> coalesced epilogue.
// Used by qkv (128x64).
// ---------------------------------------------------------------------------
template<int TM, int TN>
__device__ __forceinline__ void gemm_core(
    const short* __restrict__ A, const short* __restrict__ Bw,
    int m0, int n0, int K, short* smem, f32x4 (&acc)[TM / 32][TN / 32]) {
  constexpr int AF = TM / 32, BF = TN / 32;
  constexpr int AC = TM / 64, BC = TN / 64;   // staging calls (64 rows each)
  constexpr int BUFS = (TM + TN) * 32;        // shorts per buffer
  int t = threadIdx.x;
  int wave = t >> 6, lane = t & 63, quad = lane >> 4, l16 = lane & 15;
  int wr = wave >> 1, wc = wave & 1;

  size_t aoff[AC], boff[BC];
  int aldsoff[AC], bldsoff[BC];
#pragma unroll
  for (int c = 0; c < AC; ++c) {
    int p = c * 256 + t, row = p >> 2, lg = (p & 3) ^ ((row >> 1) & 3);
    aoff[c] = (size_t)(m0 + row) * K + lg * 8;
    aldsoff[c] = c * 2048 + wave * 512;
  }
#pragma unroll
  for (int c = 0; c < BC; ++c) {
    int p = c * 256 + t, row = p >> 2, lg = (p & 3) ^ ((row >> 1) & 3);
    boff[c] = (size_t)(n0 + row) * K + lg * 8;
    bldsoff[c] = TM * 32 + c * 2048 + wave * 512;
  }

  // stage tile 0 into buffer 0
#pragma unroll
  for (int c = 0; c < AC; ++c) gload16(A + aoff[c], smem + aldsoff[c]);
#pragma unroll
  for (int c = 0; c < BC; ++c) gload16(Bw + boff[c], smem + bldsoff[c]);

  int physo = (quad ^ ((l16 >> 1) & 3)) * 8;

  for (int k0 = 0; k0 < K; k0 += 32) {
    short* cbuf = smem + ((k0 >> 5) & 1) * BUFS;
    __syncthreads();  // drains tile-k0 loads; frees other buffer
    if (k0 + 32 < K) {
      short* nbuf = smem + (((k0 >> 5) & 1) ^ 1) * BUFS;
#pragma unroll
      for (int c = 0; c < AC; ++c) gload16(A + aoff[c] + k0 + 32, nbuf + aldsoff[c]);
#pragma unroll
      for (int c = 0; c < BC; ++c) gload16(Bw + boff[c] + k0 + 32, nbuf + bldsoff[c]);
    }
    bf16x8 af[AF], bfr[BF];
#pragma unroll
    for (int i = 0; i < AF; ++i)
      af[i] = *(const bf16x8*)&cbuf[(wr * (TM / 2) + i * 16 + l16) * 32 + physo];
#pragma unroll
    for (int j = 0; j < BF; ++j)
      bfr[j] = *(const bf16x8*)&cbuf[TM * 32 + (wc * (TN / 2) + j * 16 + l16) * 32 + physo];
#pragma unroll
    for (int i = 0; i < AF; ++i)
#pragma unroll
      for (int j = 0; j < BF; ++j)
        acc[i][j] = __builtin_amdgcn_mfma_f32_16x16x32_bf16(bfr[j], af[i], acc[i][j], 0, 0, 0);
  }
}

// ---------------------------------------------------------------------------
// 64x64 GEMM with BK=64: 4 blocks/CU, half the barrier/drain events of
// BK=32. Staging/read = fattn's verified 8-chunk XOR swizzle (sw = row&7).
// Used for proj, FF1, FF2.
// ---------------------------------------------------------------------------
__global__ __launch_bounds__(256) void mgemm64_kernel(
    const short* __restrict__ A, const short* __restrict__ Bw,
    const float* __restrict__ bias, const float* __restrict__ res,
    void* __restrict__ C, int N, int K, int dorelu, int bf16out) {
  __shared__ __align__(16) short smem[2 * 8192];  // 2 bufs x (64A+64B)x64
  f32x4 acc[2][2];
  f32x4 zf = {0.f, 0.f, 0.f, 0.f};
#pragma unroll
  for (int i = 0; i < 2; ++i)
#pragma unroll
    for (int j = 0; j < 2; ++j) acc[i][j] = zf;
  int bx, by;
  xcd_swizzle(bx, by);
  int m0 = by * 64, n0 = bx * 64;

  int t = threadIdx.x;
  int wave = t >> 6, lane = t & 63, quad = lane >> 4, l16 = lane & 15;
  int wr = wave >> 1, wc = wave & 1;

  // staging: thread t covers chunk p=t (rows 0-31) and p=256+t (rows 32-63)
  int rA0 = t >> 3,        lg0 = (t & 7) ^ (rA0 & 7);
  int rA1 = 32 + (t >> 3), lg1 = (t & 7) ^ (rA1 & 7);
  size_t aoff0 = (size_t)(m0 + rA0) * K + lg0 * 8;
  size_t aoff1 = (size_t)(m0 + rA1) * K + lg1 * 8;
  size_t boff0 = (size_t)(n0 + rA0) * K + lg0 * 8;
  size_t boff1 = (size_t)(n0 + rA1) * K + lg1 * 8;
  int lo0 = wave * 512, lo1 = 2048 + wave * 512;

  // prologue: stage tile 0 into buffer 0
  gload16(A + aoff0, smem + lo0);
  gload16(A + aoff1, smem + lo1);
  gload16(Bw + boff0, smem + 4096 + lo0);
  gload16(Bw + boff1, smem + 4096 + lo1);

  int sw = l16 & 7;

  for (int k0 = 0; k0 < K; k0 += 64) {
    short* cbuf = smem + ((k0 >> 6) & 1) * 8192;
    __syncthreads();  // drains tile-k0 loads; frees other buffer
    if (k0 + 64 < K) {
      short* nbuf = smem + (((k0 >> 6) & 1) ^ 1) * 8192;
      gload16(A + aoff0 + k0 + 64, nbuf + lo0);
      gload16(A + aoff1 + k0 + 64, nbuf + lo1);
      gload16(Bw + boff0 + k0 + 64, nbuf + 4096 + lo0);
      gload16(Bw + boff1 + k0 + 64, nbuf + 4096 + lo1);
    }
    bf16x8 af0[2], af1[2], bf0[2], bf1[2];
#pragma unroll
    for (int i = 0; i < 2; ++i) {
      int r = wr * 32 + i * 16 + l16;
      af0[i] = *(const bf16x8*)&cbuf[r * 64 + ((quad ^ sw) * 8)];
      af1[i] = *(const bf16x8*)&cbuf[r * 64 + (((4 + quad) ^ sw) * 8)];
    }
#pragma unroll
    for (int j = 0; j < 2; ++j) {
      int r = wc * 32 + j * 16 + l16;
      bf0[j] = *(const bf16x8*)&cbuf[4096 + r * 64 + ((quad ^ sw) * 8)];
      bf1[j] = *(const bf16x8*)&cbuf[4096 + r * 64 + (((4 + quad) ^ sw) * 8)];
    }
#pragma unroll
    for (int i = 0; i < 2; ++i)
#pragma unroll
      for (int j = 0; j < 2; ++j) {
        acc[i][j] = __builtin_amdgcn_mfma_f32_16x16x32_bf16(bf0[j], af0[i], acc[i][j], 0, 0, 0);
        acc[i][j] = __builtin_amdgcn_mfma_f32_16x16x32_bf16(bf1[j], af1[i], acc[i][j], 0, 0, 0);
      }
  }

  // epilogue
#pragma unroll
  for (int i = 0; i < 2; ++i) {
    int m = m0 + wr * 32 + i * 16 + l16;
#pragma unroll
    for (int j = 0; j < 2; ++j) {
      int nb = n0 + wc * 32 + j * 16 + quad * 4;
      float4 bv = *(const float4*)&bias[nb];
      float v[4] = {acc[i][j][0] + bv.x, acc[i][j][1] + bv.y,
                    acc[i][j][2] + bv.z, acc[i][j][3] + bv.w};
      if (dorelu) {
#pragma unroll
        for (int r = 0; r < 4; ++r) v[r] = fmaxf(v[r], 0.0f);
      }
      size_t off = (size_t)m * N + nb;
      if (res) {
        float4 rv = *(const float4*)(res + off);
        v[0] += rv.x; v[1] += rv.y; v[2] += rv.z; v[3] += rv.w;
      }
      if (bf16out) {
        short tmp[4] = {f2bf(v[0]), f2bf(v[1]), f2bf(v[2]), f2bf(v[3])};
        *(int2*)((short*)C + off) = *(int2*)tmp;
      } else {
        float4 outv = {v[0], v[1], v[2], v[3]};
        *(float4*)((float*)C + off) = outv;
      }
    }
  }
}

// ---------------------------------------------------------------------------
// Fused QKV GEMM, TM=128 TN=64 (v2): grid (24,64) = 1536 blocks -> 6
// blocks/CU (24 waves, 2x the old 128x128's TLP; LDS 24.6 KB).
// q scaled by SCALE_Q; v written transposed per-head via Ts[64][136].
// ---------------------------------------------------------------------------
__global__ __launch_bounds__(256) void qkv_kernel(
    const short* __restrict__ A, const short* __restrict__ Bw,
    const float* __restrict__ bq, const float* __restrict__ bk,
    const float* __restrict__ bv,
    short* __restrict__ q, short* __restrict__ k, short* __restrict__ vt) {
  __shared__ __align__(16) short smem[12288];  // 2 bufs x (128A+64B)x32; Ts 64x136
  f32x4 acc[4][2];
  f32x4 zf = {0.f, 0.f, 0.f, 0.f};
#pragma unroll
  for (int i = 0; i < 4; ++i)
#pragma unroll
    for (int j = 0; j < 2; ++j) acc[i][j] = zf;
  int bx, by;
  xcd_swizzle(bx, by);
  int m0 = by * 128, n0 = bx * 64;
  gemm_core<128, 64>(A, Bw, m0, n0, DM, smem, acc);

  int t = threadIdx.x;
  int wave = t >> 6, lane = t & 63, quad = lane >> 4, l16 = lane & 15;
  int wr = wave >> 1, wc = wave & 1;

  if (n0 < 1024) {
    short* out = (n0 < 512) ? q : k;
    const float* bias = (n0 < 512) ? bq + n0 : bk + (n0 - 512);
    float scale = (n0 < 512) ? SCALE_Q : 1.0f;
    int ncol0 = (n0 < 512) ? n0 : n0 - 512;
#pragma unroll
    for (int i = 0; i < 4; ++i) {
      int m = m0 + wr * 64 + i * 16 + l16;
#pragma unroll
      for (int j = 0; j < 2; ++j) {
        int nb = wc * 32 + j * 16 + quad * 4;
        float4 bvv = *(const float4*)&bias[nb];
        short tmp[4];
        tmp[0] = f2bf((acc[i][j][0] + bvv.x) * scale);
        tmp[1] = f2bf((acc[i][j][1] + bvv.y) * scale);
        tmp[2] = f2bf((acc[i][j][2] + bvv.z) * scale);
        tmp[3] = f2bf((acc[i][j][3] + bvv.w) * scale);
        *(int2*)(out + (size_t)m * DM + ncol0 + nb) = *(int2*)tmp;
      }
    }
  } else {
    const float* bias = bv + (n0 - 1024);
    __syncthreads();
    short* Ts = smem;  // [64][136]: Ts[n][m], n in 0..63, m in 0..127
#pragma unroll
    for (int i = 0; i < 4; ++i) {
      int ml = wr * 64 + i * 16 + l16;
#pragma unroll
      for (int j = 0; j < 2; ++j) {
        int nb = wc * 32 + j * 16 + quad * 4;
        float4 bvv = *(const float4*)&bias[nb];
        Ts[(nb + 0) * 136 + ml] = f2bf(acc[i][j][0] + bvv.x);
        Ts[(nb + 1) * 136 + ml] = f2bf(acc[i][j][1] + bvv.y);
        Ts[(nb + 2) * 136 + ml] = f2bf(acc[i][j][2] + bvv.z);
        Ts[(nb + 3) * 136 + ml] = f2bf(acc[i][j][3] + bvv.w);
      }
    }
    __syncthreads();
    // copy-out: 4 threads per n-row, 32 contiguous m each (coalesced quads)
    int nl = t >> 2, seg = (t & 3) * 32;
    int gn = (n0 - 1024) + nl;        // 64 | n0 -> single head per tile
    int hh = gn >> 6, dk = gn & 63;
    int bidx = m0 >> 11, s0 = (m0 & 2047) + seg;
    short* dst = vt + ((size_t)((bidx * NH + hh) * DK + dk)) * SEQ + s0;
    const short* srcT = &Ts[nl * 136 + seg];
#pragma unroll
    for (int i2 = 0; i2 < 32; i2 += 8)
      *(int4*)(dst + i2) = *(const int4*)(srcT + i2);
  }
}

// ---------------------------------------------------------------------------
// Flash attention v10 (best measured: 46.2 us): 64 q-rows/block, 1024
// blocks, dbuf async K/V, diag-split, XCD-grouped heavy-first, unpadded
// XOR-swizzled P buffer. LDS 40960 B. (v12 in-reg exchange reverted:
// shfl_xor = ds_bpermute, costs more than the P LDS round-trip.)
// ---------------------------------------------------------------------------
template<bool DIAG>
static __device__ __forceinline__ void attn_tile(
    const short* __restrict__ KsC, const short* __restrict__ VsC,
    short* __restrict__ Psw, const bf16x8& qf0, const bf16x8& qf1,
    f32x4 (&o_acc)[4], float& l_part, int quad, int l16,
    int keyb0, int qrow) {
  f32x4 zf = {0.f, 0.f, 0.f, 0.f};
  int sw = l16 & 7;  // krow & 7 == l16 & 7 since nt*16 % 8 == 0

  // S^T: key = nt*16+quad*4+r (rows), qrow = cols (lane-local l16)
#pragma unroll
  for (int nt = 0; nt < 4; ++nt) {
    int krow = nt * 16 + l16;
    bf16x8 ka0 = *(const bf16x8*)&KsC[krow * 64 + ((quad ^ sw) * 8)];
    bf16x8 ka1 = *(const bf16x8*)&KsC[krow * 64 + (((4 + quad) ^ sw) * 8)];
    f32x4 s = __builtin_amdgcn_mfma_f32_16x16x32_bf16(ka0, qf0, zf, 0, 0, 0);
    s = __builtin_amdgcn_mfma_f32_16x16x32_bf16(ka1, qf1, s, 0, 0, 0);
    int keyb = keyb0 + nt * 16 + quad * 4;
    float pr[4];
#pragma unroll
    for (int r = 0; r < 4; ++r) {
      float e = exp2f(s[r]);
      pr[r] = (DIAG && (keyb + r > qrow)) ? 0.0f : e;
      l_part += pr[r];
    }
    // truncation-pack two f32 -> packed bf16x2 in 1 v_perm each
    unsigned pk0 = __builtin_amdgcn_perm(
        __float_as_uint(pr[1]), __float_as_uint(pr[0]), 0x07060302u);
    unsigned pk1 = __builtin_amdgcn_perm(
        __float_as_uint(pr[3]), __float_as_uint(pr[2]), 0x07060302u);
    int2 w = {(int)pk0, (int)pk1};
    // P row l16, logical chunk = nt*2 + (quad>>1), XOR-swizzled placement
    *(int2*)&Psw[l16 * 64 + (((nt * 2 + (quad >> 1)) ^ sw) << 3) +
                 ((quad & 1) * 4)] = w;
  }

  // PV: O += V^T P  (A = V^T rows = dk, B = P cols = qrow)
  bf16x8 apf0 = *(const bf16x8*)&Psw[l16 * 64 + ((quad ^ sw) * 8)];
  bf16x8 apf1 = *(const bf16x8*)&Psw[l16 * 64 + (((4 + quad) ^ sw) * 8)];
  __builtin_amdgcn_s_setprio(1);
#pragma unroll
  for (int nt2 = 0; nt2 < 4; ++nt2) {
    int vrow = nt2 * 16 + l16;
    bf16x8 vf0 = *(const bf16x8*)&VsC[vrow * 64 + ((quad ^ sw) * 8)];
    bf16x8 vf1 = *(const bf16x8*)&VsC[vrow * 64 + (((4 + quad) ^ sw) * 8)];
    o_acc[nt2] = __builtin_amdgcn_mfma_f32_16x16x32_bf16(vf0, apf0, o_acc[nt2], 0, 0, 0);
    o_acc[nt2] = __builtin_amdgcn_mfma_f32_16x16x32_bf16(vf1, apf1, o_acc[nt2], 0, 0, 0);
  }
  __builtin_amdgcn_s_setprio(0);
}

__global__ __launch_bounds__(256) void fattn_kernel(
    const short* __restrict__ Q, const short* __restrict__ Kg,
    const short* __restrict__ Vt, short* __restrict__ O) {
  // XCD-grouped swizzle: id%8 ~ XCD. Each XCD owns groups c*4..c*4+3,
  // interleaved by descending qt so all 32 heavy blocks dispatch first.
  int id = blockIdx.x + 32 * (blockIdx.y + NH * blockIdx.z);
  int c = id & 7, j = id >> 3;
  int g = c * 4 + (j & 3);          // (b,h) group, 4 per XCD
  int qt = 31 - (j >> 2);           // heavy-first within XCD
  int h = g & 7, b = g >> 3;
  int q0 = qt * 64;
  int t = threadIdx.x, wave = t >> 6, lane = t & 63, quad = lane >> 4, l16 = lane & 15;

  __shared__ __align__(16) short Ks[2][64 * 64];   // [key][dk], 8-chunk swizzle, dbuf
  __shared__ __align__(16) short Vs[2][64 * 64];   // [dk][key], 8-chunk swizzle, dbuf
  __shared__ __align__(16) short Ps[4][16 * 64];   // per-wave P, 8-chunk swizzle

  f32x4 zf = {0.f, 0.f, 0.f, 0.f};
  const short* qp = Q + ((size_t)(b * SEQ + q0 + wave * 16 + l16)) * DM + h * DK;
  bf16x8 qf0 = *(const bf16x8*)(qp + quad * 8);
  bf16x8 qf1 = *(const bf16x8*)(qp + 32 + quad * 8);

  f32x4 o_acc[4];   // regs = dk (quad*4+r within nt2*16), lane col = qrow
  float l_part = 0.0f;
#pragma unroll
  for (int i = 0; i < 4; ++i) o_acc[i] = zf;

  const short* kb = Kg + ((size_t)(b * SEQ)) * DM + h * DK;
  const short* vb = Vt + ((size_t)((b * NH + h) * DK)) * SEQ;

  // staging addresses: thread t covers two 16B chunks
  int row0 = t >> 3,         lg0 = (t & 7) ^ (row0 & 7);
  int row1 = (256 + t) >> 3, lg1 = ((256 + t) & 7) ^ (row1 & 7);
  const short* kp0 = kb + (size_t)row0 * DM + lg0 * 8;
  const short* kp1 = kb + (size_t)row1 * DM + lg1 * 8;
  const short* vp0 = vb + (size_t)row0 * SEQ + lg0 * 8;
  const short* vp1 = vb + (size_t)row1 * SEQ + lg1 * 8;
  int lo0 = wave * 512, lo1 = 2048 + wave * 512;

#define STAGE_KV(B) do {                                     \
    gload16(kp0, &Ks[B][lo0]); gload16(kp1, &Ks[B][lo1]);    \
    gload16(vp0, &Vs[B][lo0]); gload16(vp1, &Vs[B][lo1]);    \
    kp0 += 64 * DM; kp1 += 64 * DM; vp0 += 64; vp1 += 64; } while (0)

  // prologue: stage tile 0 into buffer 0
  STAGE_KV(0);

  int qrow = q0 + wave * 16 + l16;
  short* Psw = &Ps[wave][0];

  int buf = 0;
  for (int kt = 0; kt < qt; ++kt) {
    __syncthreads();               // drains tile-kt loads; frees other buffer
    STAGE_KV(buf ^ 1);
    attn_tile<false>(&Ks[buf][0], &Vs[buf][0], Psw, qf0, qf1,
                     o_acc, l_part, quad, l16, 0, qrow);
    buf ^= 1;
  }
  __syncthreads();                 // drains diag-tile loads
  attn_tile<true>(&Ks[buf][0], &Vs[buf][0], Psw, qf0, qf1,
                  o_acc, l_part, quad, l16, qt * 64, qrow);

  float lf = l_part;
  lf += __shfl_xor(lf, 16);
  lf += __shfl_xor(lf, 32);   // all lanes sharing l16 hold full row sum
  float inv = 1.0f / lf;      // this lane's qrow
  short* orow = O + ((size_t)(b * SEQ) + qrow) * DM + h * DK;
#pragma unroll
  for (int nt2 = 0; nt2 < 4; ++nt2) {
    short tmp[4];
#pragma unroll
    for (int r = 0; r < 4; ++r) tmp[r] = f2bf(o_acc[nt2][r] * inv);
    *(int2*)(orow + nt2 * 16 + quad * 4) = *(int2*)tmp;
  }
#undef STAGE_KV
}

// ---------------------------------------------------------------------------
extern "C" void kernel_launch(void* const* d_in, const int* in_sizes, int n_in,
                              void* d_out, int out_size, void* d_ws, size_t ws_size,
                              hipStream_t stream) {
  const float* x   = (const float*)d_in[0];
  const float* Wq  = (const float*)d_in[1];
  const float* bq  = (const float*)d_in[2];
  const float* Wk  = (const float*)d_in[3];
  const float* bk  = (const float*)d_in[4];
  const float* Wv  = (const float*)d_in[5];
  const float* bv  = (const float*)d_in[6];
  const float* Wp  = (const float*)d_in[7];
  const float* bp  = (const float*)d_in[8];
  const float* W1  = (const float*)d_in[9];
  const float* b1  = (const float*)d_in[10];
  const float* W2  = (const float*)d_in[11];
  const float* b2  = (const float*)d_in[12];
  const float* g1  = (const float*)d_in[13];
  const float* be1 = (const float*)d_in[14];
  const float* g2  = (const float*)d_in[15];
  const float* be2 = (const float*)d_in[16];
  float* out = (float*)d_out;

  char* wsb = (char*)d_ws;
  const size_t SB = (size_t)BT * DM * 2;  // 8 MB
  short* h    = (short*)(wsb);
  short* q    = (short*)(wsb + SB);
  short* k    = (short*)(wsb + 2 * SB);
  short* vt   = (short*)(wsb + 3 * SB);
  short* o    = (short*)(wsb + 4 * SB);
  float* x2   = (float*)(wsb + 5 * SB);                       // 16 MB
  short* h2   = (short*)(wsb + 5 * SB + (size_t)BT * DM * 4);
  short* ff   = (short*)(wsb + 6 * SB + (size_t)BT * DM * 4); // 32 MB
  short* wqkv = (short*)(wsb + 6 * SB + (size_t)BT * DM * 4 + (size_t)BT * FF * 2);
  short* wpt  = wqkv + 1536 * 512;
  short* w1t  = wpt + 512 * 512;
  short* w2t  = w1t + 2048 * 512;

  dim3 blk(256);

  wconv_kernel<<<dim3(768), blk, 0, stream>>>(Wq, Wk, Wv, Wp, W1, W2,
                                              wqkv, wpt, w1t, w2t);
  ln_kernel<<<BT, blk, 0, stream>>>(x, g1, be1, h);

  qkv_kernel<<<dim3(24, 64), blk, 0, stream>>>(h, wqkv, bq, bk, bv, q, k, vt);

  fattn_kernel<<<dim3(32, NH, BATCH), blk, 0, stream>>>(q, k, vt, o);

  mgemm64_kernel<<<dim3(8, 128), blk, 0, stream>>>(o, wpt, bp, x, x2, DM, DM, 0, 0);
  ln_kernel<<<BT, blk, 0, stream>>>(x2, g2, be2, h2);
  mgemm64_kernel<<<dim3(32, 128), blk, 0, stream>>>(h2, w1t, b1, nullptr, ff, FF, DM, 1, 1);
  mgemm64_kernel<<<dim3(8, 128), blk, 0, stream>>>(ff, w2t, b2, x2, out, DM, FF, 0, 0);
}

// Round 12
// 251.373 us; speedup vs baseline: 1.0125x; 1.0125x over previous
//
#include <hip/hip_runtime.h>
#include <hip/hip_bf16.h>
#include <math.h>

#define BATCH 4
#define SEQ   2048
#define DM    512
#define NH    8
#define DK    64
#define FF    2048
#define BT    (BATCH * SEQ)   // 8192

// q pre-scale: 0.125 * log2(e)  -> softmax uses exp2 directly
#define SCALE_Q 0.18033688011112042f

typedef short bf16x8 __attribute__((ext_vector_type(8)));
typedef float f32x4  __attribute__((ext_vector_type(4)));

static __device__ inline short f2bf(float f) {
  union { float f; unsigned u; } v; v.f = f;
  unsigned r = (v.u + 0x7fffu + ((v.u >> 16) & 1u)) >> 16;
  return (short)r;
}

// async 16B global->LDS (gfx950). LDS dest = wave-uniform base + lane*16.
static __device__ __forceinline__ void gload16(const short* g, short* l) {
  __builtin_amdgcn_global_load_lds(
      (const __attribute__((address_space(1))) void*)g,
      (__attribute__((address_space(3))) void*)l, 16, 0, 0);
}

// Bijective XCD-chunk swizzle: XCD c owns logical ids [c*nwg/8, (c+1)*nwg/8).
static __device__ __forceinline__ void xcd_swizzle(int& bx, int& by) {
  int gx = gridDim.x;
  int nwg = gx * gridDim.y;
  int id = blockIdx.x + gx * blockIdx.y;
  int nid = (id & 7) * (nwg >> 3) + (id >> 3);
  bx = nid % gx;
  by = nid / gx;
}

// ---------------------------------------------------------------------------
// LayerNorm: one block per row of 512, fp32 in -> bf16 out
// ---------------------------------------------------------------------------
__global__ __launch_bounds__(256) void ln_kernel(
    const float* __restrict__ x, const float* __restrict__ gamma,
    const float* __restrict__ beta, short* __restrict__ out) {
  int row = blockIdx.x;
  const float* xr = x + (size_t)row * DM;
  int t = threadIdx.x;
  float v0 = xr[t], v1 = xr[t + 256];
  float s = v0 + v1;
  float sq = v0 * v0 + v1 * v1;
  for (int off = 32; off; off >>= 1) {
    s  += __shfl_xor(s, off);
    sq += __shfl_xor(sq, off);
  }
  __shared__ float ssum[4], ssq[4];
  int wave = t >> 6, lane = t & 63;
  if (lane == 0) { ssum[wave] = s; ssq[wave] = sq; }
  __syncthreads();
  if (t == 0) {
    float S = ssum[0] + ssum[1] + ssum[2] + ssum[3];
    float Q = ssq[0] + ssq[1] + ssq[2] + ssq[3];
    float mu = S * (1.0f / DM);
    float var = Q * (1.0f / DM) - mu * mu;
    ssum[0] = mu;
    ssq[0] = rsqrtf(var + 1e-5f);
  }
  __syncthreads();
  float mu = ssum[0], rstd = ssq[0];
  short* orow = out + (size_t)row * DM;
  orow[t]       = f2bf((v0 - mu) * rstd * gamma[t]       + beta[t]);
  orow[t + 256] = f2bf((v1 - mu) * rstd * gamma[t + 256] + beta[t + 256]);
}

// ---------------------------------------------------------------------------
// Weight convert+transpose fp32 [R][C] -> bf16 [C][R]. Flat 768-block grid.
// ---------------------------------------------------------------------------
__global__ __launch_bounds__(256) void wconv_kernel(
    const float* Wq, const float* Wk, const float* Wv,
    const float* Wp, const float* W1, const float* W2,
    short* wqkv, short* wpt, short* w1t, short* w2t) {
  int id = blockIdx.x;
  const float* src; short* dst; int R, C, tx, ty;
  if (id < 192) {                      // 24 sub-matrices of 512x64, 8 blocks each
    int z = id >> 3;
    int m = z >> 3, hh = z & 7;
    const float* s0 = (m == 0) ? Wq : (m == 1) ? Wk : Wv;
    src = s0 + (size_t)hh * 512 * 64;
    dst = wqkv + ((size_t)(m * 512 + hh * 64)) * 512;
    R = 512; C = 64; tx = 0; ty = id & 7;
  } else if (id < 256) {               // Wp 512x512: 64 blocks
    int w = id - 192; src = Wp; dst = wpt; R = 512; C = 512;
    tx = w & 7; ty = w >> 3;
  } else if (id < 512) {               // W1 512x2048: 256 blocks
    int w = id - 256; src = W1; dst = w1t; R = 512; C = 2048;
    tx = w & 31; ty = w >> 5;
  } else {                             // W2 2048x512: 256 blocks
    int w = id - 512; src = W2; dst = w2t; R = 2048; C = 512;
    tx = w & 7; ty = w >> 3;
  }
  __shared__ float Ts[64][68];
  int t = threadIdx.x;
  int r = t >> 2, c0 = (t & 3) * 16;
  const float* sp = src + (size_t)(ty * 64 + r) * C + tx * 64 + c0;
#pragma unroll
  for (int i = 0; i < 16; i += 4) {
    float4 v = *(const float4*)(sp + i);
    Ts[c0 + i + 0][r] = v.x; Ts[c0 + i + 1][r] = v.y;
    Ts[c0 + i + 2][r] = v.z; Ts[c0 + i + 3][r] = v.w;
  }
  __syncthreads();
  short* dp = dst + (size_t)(tx * 64 + r) * R + ty * 64 + c0;
  short tmp[16];
#pragma unroll
  for (int i = 0; i < 16; ++i) tmp[i] = f2bf(Ts[r][c0 + i]);
  *(int4*)(dp)     = *(int4*)&tmp[0];
  *(int4*)(dp + 8) = *(int4*)&tmp[8];
}

// ---------------------------------------------------------------------------
// GEMM core (R8): BK=32, double-buffered async staging, operand-swapped
// MFMA. Used by qkv (128x64).
// ---------------------------------------------------------------------------
template<int TM, int TN>
__device__ __forceinline__ void gemm_core(
    const short* __restrict__ A, const short* __restrict__ Bw,
    int m0, int n0, int K, short* smem, f32x4 (&acc)[TM / 32][TN / 32]) {
  constexpr int AF = TM / 32, BF = TN / 32;
  constexpr int AC = TM / 64, BC = TN / 64;   // staging calls (64 rows each)
  constexpr int BUFS = (TM + TN) * 32;        // shorts per buffer
  int t = threadIdx.x;
  int wave = t >> 6, lane = t & 63, quad = lane >> 4, l16 = lane & 15;
  int wr = wave >> 1, wc = wave & 1;

  size_t aoff[AC], boff[BC];
  int aldsoff[AC], bldsoff[BC];
#pragma unroll
  for (int c = 0; c < AC; ++c) {
    int p = c * 256 + t, row = p >> 2, lg = (p & 3) ^ ((row >> 1) & 3);
    aoff[c] = (size_t)(m0 + row) * K + lg * 8;
    aldsoff[c] = c * 2048 + wave * 512;
  }
#pragma unroll
  for (int c = 0; c < BC; ++c) {
    int p = c * 256 + t, row = p >> 2, lg = (p & 3) ^ ((row >> 1) & 3);
    boff[c] = (size_t)(n0 + row) * K + lg * 8;
    bldsoff[c] = TM * 32 + c * 2048 + wave * 512;
  }

  // stage tile 0 into buffer 0
#pragma unroll
  for (int c = 0; c < AC; ++c) gload16(A + aoff[c], smem + aldsoff[c]);
#pragma unroll
  for (int c = 0; c < BC; ++c) gload16(Bw + boff[c], smem + bldsoff[c]);

  int physo = (quad ^ ((l16 >> 1) & 3)) * 8;

  for (int k0 = 0; k0 < K; k0 += 32) {
    short* cbuf = smem + ((k0 >> 5) & 1) * BUFS;
    __syncthreads();  // drains tile-k0 loads; frees other buffer
    if (k0 + 32 < K) {
      short* nbuf = smem + (((k0 >> 5) & 1) ^ 1) * BUFS;
#pragma unroll
      for (int c = 0; c < AC; ++c) gload16(A + aoff[c] + k0 + 32, nbuf + aldsoff[c]);
#pragma unroll
      for (int c = 0; c < BC; ++c) gload16(Bw + boff[c] + k0 + 32, nbuf + bldsoff[c]);
    }
    bf16x8 af[AF], bfr[BF];
#pragma unroll
    for (int i = 0; i < AF; ++i)
      af[i] = *(const bf16x8*)&cbuf[(wr * (TM / 2) + i * 16 + l16) * 32 + physo];
#pragma unroll
    for (int j = 0; j < BF; ++j)
      bfr[j] = *(const bf16x8*)&cbuf[TM * 32 + (wc * (TN / 2) + j * 16 + l16) * 32 + physo];
#pragma unroll
    for (int i = 0; i < AF; ++i)
#pragma unroll
      for (int j = 0; j < BF; ++j)
        acc[i][j] = __builtin_amdgcn_mfma_f32_16x16x32_bf16(bfr[j], af[i], acc[i][j], 0, 0, 0);
  }
}

// ---------------------------------------------------------------------------
// 64x64 GEMM with BK=64: 4 blocks/CU, half the barrier/drain events of
// BK=32. Used for proj, FF1, FF2.
// ---------------------------------------------------------------------------
__global__ __launch_bounds__(256) void mgemm64_kernel(
    const short* __restrict__ A, const short* __restrict__ Bw,
    const float* __restrict__ bias, const float* __restrict__ res,
    void* __restrict__ C, int N, int K, int dorelu, int bf16out) {
  __shared__ __align__(16) short smem[2 * 8192];  // 2 bufs x (64A+64B)x64
  f32x4 acc[2][2];
  f32x4 zf = {0.f, 0.f, 0.f, 0.f};
#pragma unroll
  for (int i = 0; i < 2; ++i)
#pragma unroll
    for (int j = 0; j < 2; ++j) acc[i][j] = zf;
  int bx, by;
  xcd_swizzle(bx, by);
  int m0 = by * 64, n0 = bx * 64;

  int t = threadIdx.x;
  int wave = t >> 6, lane = t & 63, quad = lane >> 4, l16 = lane & 15;
  int wr = wave >> 1, wc = wave & 1;

  int rA0 = t >> 3,        lg0 = (t & 7) ^ (rA0 & 7);
  int rA1 = 32 + (t >> 3), lg1 = (t & 7) ^ (rA1 & 7);
  size_t aoff0 = (size_t)(m0 + rA0) * K + lg0 * 8;
  size_t aoff1 = (size_t)(m0 + rA1) * K + lg1 * 8;
  size_t boff0 = (size_t)(n0 + rA0) * K + lg0 * 8;
  size_t boff1 = (size_t)(n0 + rA1) * K + lg1 * 8;
  int lo0 = wave * 512, lo1 = 2048 + wave * 512;

  gload16(A + aoff0, smem + lo0);
  gload16(A + aoff1, smem + lo1);
  gload16(Bw + boff0, smem + 4096 + lo0);
  gload16(Bw + boff1, smem + 4096 + lo1);

  int sw = l16 & 7;

  for (int k0 = 0; k0 < K; k0 += 64) {
    short* cbuf = smem + ((k0 >> 6) & 1) * 8192;
    __syncthreads();
    if (k0 + 64 < K) {
      short* nbuf = smem + (((k0 >> 6) & 1) ^ 1) * 8192;
      gload16(A + aoff0 + k0 + 64, nbuf + lo0);
      gload16(A + aoff1 + k0 + 64, nbuf + lo1);
      gload16(Bw + boff0 + k0 + 64, nbuf + 4096 + lo0);
      gload16(Bw + boff1 + k0 + 64, nbuf + 4096 + lo1);
    }
    bf16x8 af0[2], af1[2], bf0[2], bf1[2];
#pragma unroll
    for (int i = 0; i < 2; ++i) {
      int r = wr * 32 + i * 16 + l16;
      af0[i] = *(const bf16x8*)&cbuf[r * 64 + ((quad ^ sw) * 8)];
      af1[i] = *(const bf16x8*)&cbuf[r * 64 + (((4 + quad) ^ sw) * 8)];
    }
#pragma unroll
    for (int j = 0; j < 2; ++j) {
      int r = wc * 32 + j * 16 + l16;
      bf0[j] = *(const bf16x8*)&cbuf[4096 + r * 64 + ((quad ^ sw) * 8)];
      bf1[j] = *(const bf16x8*)&cbuf[4096 + r * 64 + (((4 + quad) ^ sw) * 8)];
    }
#pragma unroll
    for (int i = 0; i < 2; ++i)
#pragma unroll
      for (int j = 0; j < 2; ++j) {
        acc[i][j] = __builtin_amdgcn_mfma_f32_16x16x32_bf16(bf0[j], af0[i], acc[i][j], 0, 0, 0);
        acc[i][j] = __builtin_amdgcn_mfma_f32_16x16x32_bf16(bf1[j], af1[i], acc[i][j], 0, 0, 0);
      }
  }

#pragma unroll
  for (int i = 0; i < 2; ++i) {
    int m = m0 + wr * 32 + i * 16 + l16;
#pragma unroll
    for (int j = 0; j < 2; ++j) {
      int nb = n0 + wc * 32 + j * 16 + quad * 4;
      float4 bv = *(const float4*)&bias[nb];
      float v[4] = {acc[i][j][0] + bv.x, acc[i][j][1] + bv.y,
                    acc[i][j][2] + bv.z, acc[i][j][3] + bv.w};
      if (dorelu) {
#pragma unroll
        for (int r = 0; r < 4; ++r) v[r] = fmaxf(v[r], 0.0f);
      }
      size_t off = (size_t)m * N + nb;
      if (res) {
        float4 rv = *(const float4*)(res + off);
        v[0] += rv.x; v[1] += rv.y; v[2] += rv.z; v[3] += rv.w;
      }
      if (bf16out) {
        short tmp[4] = {f2bf(v[0]), f2bf(v[1]), f2bf(v[2]), f2bf(v[3])};
        *(int2*)((short*)C + off) = *(int2*)tmp;
      } else {
        float4 outv = {v[0], v[1], v[2], v[3]};
        *(float4*)((float*)C + off) = outv;
      }
    }
  }
}

// ---------------------------------------------------------------------------
// Fused QKV GEMM, TM=128 TN=64: grid (24,64) = 1536 blocks -> 6 blocks/CU.
// ---------------------------------------------------------------------------
__global__ __launch_bounds__(256) void qkv_kernel(
    const short* __restrict__ A, const short* __restrict__ Bw,
    const float* __restrict__ bq, const float* __restrict__ bk,
    const float* __restrict__ bv,
    short* __restrict__ q, short* __restrict__ k, short* __restrict__ vt) {
  __shared__ __align__(16) short smem[12288];  // 2 bufs x (128A+64B)x32; Ts 64x136
  f32x4 acc[4][2];
  f32x4 zf = {0.f, 0.f, 0.f, 0.f};
#pragma unroll
  for (int i = 0; i < 4; ++i)
#pragma unroll
    for (int j = 0; j < 2; ++j) acc[i][j] = zf;
  int bx, by;
  xcd_swizzle(bx, by);
  int m0 = by * 128, n0 = bx * 64;
  gemm_core<128, 64>(A, Bw, m0, n0, DM, smem, acc);

  int t = threadIdx.x;
  int wave = t >> 6, lane = t & 63, quad = lane >> 4, l16 = lane & 15;
  int wr = wave >> 1, wc = wave & 1;

  if (n0 < 1024) {
    short* out = (n0 < 512) ? q : k;
    const float* bias = (n0 < 512) ? bq + n0 : bk + (n0 - 512);
    float scale = (n0 < 512) ? SCALE_Q : 1.0f;
    int ncol0 = (n0 < 512) ? n0 : n0 - 512;
#pragma unroll
    for (int i = 0; i < 4; ++i) {
      int m = m0 + wr * 64 + i * 16 + l16;
#pragma unroll
      for (int j = 0; j < 2; ++j) {
        int nb = wc * 32 + j * 16 + quad * 4;
        float4 bvv = *(const float4*)&bias[nb];
        short tmp[4];
        tmp[0] = f2bf((acc[i][j][0] + bvv.x) * scale);
        tmp[1] = f2bf((acc[i][j][1] + bvv.y) * scale);
        tmp[2] = f2bf((acc[i][j][2] + bvv.z) * scale);
        tmp[3] = f2bf((acc[i][j][3] + bvv.w) * scale);
        *(int2*)(out + (size_t)m * DM + ncol0 + nb) = *(int2*)tmp;
      }
    }
  } else {
    const float* bias = bv + (n0 - 1024);
    __syncthreads();
    short* Ts = smem;  // [64][136]: Ts[n][m]
#pragma unroll
    for (int i = 0; i < 4; ++i) {
      int ml = wr * 64 + i * 16 + l16;
#pragma unroll
      for (int j = 0; j < 2; ++j) {
        int nb = wc * 32 + j * 16 + quad * 4;
        float4 bvv = *(const float4*)&bias[nb];
        Ts[(nb + 0) * 136 + ml] = f2bf(acc[i][j][0] + bvv.x);
        Ts[(nb + 1) * 136 + ml] = f2bf(acc[i][j][1] + bvv.y);
        Ts[(nb + 2) * 136 + ml] = f2bf(acc[i][j][2] + bvv.z);
        Ts[(nb + 3) * 136 + ml] = f2bf(acc[i][j][3] + bvv.w);
      }
    }
    __syncthreads();
    int nl = t >> 2, seg = (t & 3) * 32;
    int gn = (n0 - 1024) + nl;
    int hh = gn >> 6, dk = gn & 63;
    int bidx = m0 >> 11, s0 = (m0 & 2047) + seg;
    short* dst = vt + ((size_t)((bidx * NH + hh) * DK + dk)) * SEQ + s0;
    const short* srcT = &Ts[nl * 136 + seg];
#pragma unroll
    for (int i2 = 0; i2 < 32; i2 += 8)
      *(int4*)(dst + i2) = *(const int4*)(srcT + i2);
  }
}

// ---------------------------------------------------------------------------
// Flash attention v13: split-K. No-max softmax is linear in disjoint key
// ranges, so q-tiles qt>=16 are split into two blocks (p0: kt 0..15,
// p1: kt 16..qt incl. diag) writing unnormalized f32 partials; qt<=15
// solo blocks write O directly. Max block length 32 -> 16 tile-units
// (the measured wall was the qt=31 critical path; occupancy 24% matched
// triangular-work math exactly). Grid 1536, XCD-grouped, heavy-first.
// cmb_kernel combines partials for rows >= 1024.
// ---------------------------------------------------------------------------
template<bool DIAG>
static __device__ __forceinline__ void attn_tile(
    const short* __restrict__ KsC, const short* __restrict__ VsC,
    short* __restrict__ Psw, const bf16x8& qf0, const bf16x8& qf1,
    f32x4 (&o_acc)[4], float& l_part, int quad, int l16,
    int keyb0, int qrow) {
  f32x4 zf = {0.f, 0.f, 0.f, 0.f};
  int sw = l16 & 7;  // krow & 7 == l16 & 7 since nt*16 % 8 == 0

  // S^T: key = nt*16+quad*4+r (rows), qrow = cols (lane-local l16)
#pragma unroll
  for (int nt = 0; nt < 4; ++nt) {
    int krow = nt * 16 + l16;
    bf16x8 ka0 = *(const bf16x8*)&KsC[krow * 64 + ((quad ^ sw) * 8)];
    bf16x8 ka1 = *(const bf16x8*)&KsC[krow * 64 + (((4 + quad) ^ sw) * 8)];
    f32x4 s = __builtin_amdgcn_mfma_f32_16x16x32_bf16(ka0, qf0, zf, 0, 0, 0);
    s = __builtin_amdgcn_mfma_f32_16x16x32_bf16(ka1, qf1, s, 0, 0, 0);
    int keyb = keyb0 + nt * 16 + quad * 4;
    float pr[4];
#pragma unroll
    for (int r = 0; r < 4; ++r) {
      float e = exp2f(s[r]);
      pr[r] = (DIAG && (keyb + r > qrow)) ? 0.0f : e;
      l_part += pr[r];
    }
    unsigned pk0 = __builtin_amdgcn_perm(
        __float_as_uint(pr[1]), __float_as_uint(pr[0]), 0x07060302u);
    unsigned pk1 = __builtin_amdgcn_perm(
        __float_as_uint(pr[3]), __float_as_uint(pr[2]), 0x07060302u);
    int2 w = {(int)pk0, (int)pk1};
    *(int2*)&Psw[l16 * 64 + (((nt * 2 + (quad >> 1)) ^ sw) << 3) +
                 ((quad & 1) * 4)] = w;
  }

  // PV: O += V^T P
  bf16x8 apf0 = *(const bf16x8*)&Psw[l16 * 64 + ((quad ^ sw) * 8)];
  bf16x8 apf1 = *(const bf16x8*)&Psw[l16 * 64 + (((4 + quad) ^ sw) * 8)];
  __builtin_amdgcn_s_setprio(1);
#pragma unroll
  for (int nt2 = 0; nt2 < 4; ++nt2) {
    int vrow = nt2 * 16 + l16;
    bf16x8 vf0 = *(const bf16x8*)&VsC[vrow * 64 + ((quad ^ sw) * 8)];
    bf16x8 vf1 = *(const bf16x8*)&VsC[vrow * 64 + (((4 + quad) ^ sw) * 8)];
    o_acc[nt2] = __builtin_amdgcn_mfma_f32_16x16x32_bf16(vf0, apf0, o_acc[nt2], 0, 0, 0);
    o_acc[nt2] = __builtin_amdgcn_mfma_f32_16x16x32_bf16(vf1, apf1, o_acc[nt2], 0, 0, 0);
  }
  __builtin_amdgcn_s_setprio(0);
}

__global__ __launch_bounds__(256) void fattn_kernel(
    const short* __restrict__ Q, const short* __restrict__ Kg,
    const short* __restrict__ Vt, short* __restrict__ O,
    float* __restrict__ pscr) {
  // id -> (XCD slot c, group g = c*4+sub, work w). 48 blocks per group:
  // w 0..15:  split p0, qt = 31-w      (16 k-tiles, no diag)
  // w 16..31: split p1, qt = 31-(w-16) (qt-15 k-tiles, diag)
  // w 32..47: solo,     qt = 15-(w-32) (qt+1 k-tiles, diag)
  int id = blockIdx.x;
  int c = id & 7, j = id >> 3;
  int sub = j & 3, w = j >> 2;
  int g = c * 4 + sub;
  int h = g & 7, b = g >> 3;
  int qt, kt0, ktN, p = 0;
  bool split;
  if (w < 16)      { qt = 31 - w;        p = 0; kt0 = 0;  ktN = 16;     split = true;  }
  else if (w < 32) { qt = 31 - (w - 16); p = 1; kt0 = 16; ktN = qt + 1; split = true;  }
  else             { qt = 15 - (w - 32);        kt0 = 0;  ktN = qt + 1; split = false; }
  bool hasdiag = !(split && p == 0);
  int q0 = qt * 64;
  int t = threadIdx.x, wave = t >> 6, lane = t & 63, quad = lane >> 4, l16 = lane & 15;

  __shared__ __align__(16) short Ks[2][64 * 64];
  __shared__ __align__(16) short Vs[2][64 * 64];
  __shared__ __align__(16) short Ps[4][16 * 64];

  f32x4 zf = {0.f, 0.f, 0.f, 0.f};
  const short* qp = Q + ((size_t)(b * SEQ + q0 + wave * 16 + l16)) * DM + h * DK;
  bf16x8 qf0 = *(const bf16x8*)(qp + quad * 8);
  bf16x8 qf1 = *(const bf16x8*)(qp + 32 + quad * 8);

  f32x4 o_acc[4];
  float l_part = 0.0f;
#pragma unroll
  for (int i = 0; i < 4; ++i) o_acc[i] = zf;

  const short* kb = Kg + ((size_t)(b * SEQ)) * DM + h * DK;
  const short* vb = Vt + ((size_t)((b * NH + h) * DK)) * SEQ;

  int row0 = t >> 3,         lg0 = (t & 7) ^ (row0 & 7);
  int row1 = (256 + t) >> 3, lg1 = ((256 + t) & 7) ^ (row1 & 7);
  const short* kp0 = kb + (size_t)row0 * DM + lg0 * 8 + (size_t)kt0 * 64 * DM;
  const short* kp1 = kb + (size_t)row1 * DM + lg1 * 8 + (size_t)kt0 * 64 * DM;
  const short* vp0 = vb + (size_t)row0 * SEQ + lg0 * 8 + kt0 * 64;
  const short* vp1 = vb + (size_t)row1 * SEQ + lg1 * 8 + kt0 * 64;
  int lo0 = wave * 512, lo1 = 2048 + wave * 512;

#define STAGE_KV(B) do {                                     \
    gload16(kp0, &Ks[B][lo0]); gload16(kp1, &Ks[B][lo1]);    \
    gload16(vp0, &Vs[B][lo0]); gload16(vp1, &Vs[B][lo1]);    \
    kp0 += 64 * DM; kp1 += 64 * DM; vp0 += 64; vp1 += 64; } while (0)

  STAGE_KV(0);

  int qrow = q0 + wave * 16 + l16;
  short* Psw = &Ps[wave][0];

  int buf = 0;
  for (int kt = kt0; kt < ktN - 1; ++kt) {
    __syncthreads();
    STAGE_KV(buf ^ 1);
    attn_tile<false>(&Ks[buf][0], &Vs[buf][0], Psw, qf0, qf1,
                     o_acc, l_part, quad, l16, 0, qrow);
    buf ^= 1;
  }
  __syncthreads();
  if (hasdiag)
    attn_tile<true>(&Ks[buf][0], &Vs[buf][0], Psw, qf0, qf1,
                    o_acc, l_part, quad, l16, (ktN - 1) * 64, qrow);
  else
    attn_tile<false>(&Ks[buf][0], &Vs[buf][0], Psw, qf0, qf1,
                     o_acc, l_part, quad, l16, 0, qrow);

  float lf = l_part;
  lf += __shfl_xor(lf, 16);
  lf += __shfl_xor(lf, 32);   // all lanes sharing l16 hold full row sum

  if (!split) {
    float inv = 1.0f / lf;
    short* orow = O + ((size_t)(b * SEQ) + qrow) * DM + h * DK;
#pragma unroll
    for (int nt2 = 0; nt2 < 4; ++nt2) {
      short tmp[4];
#pragma unroll
      for (int r = 0; r < 4; ++r) tmp[r] = f2bf(o_acc[nt2][r] * inv);
      *(int2*)(orow + nt2 * 16 + quad * 4) = *(int2*)tmp;
    }
  } else {
    // scratch: po0 [32768][64] f32, po1 same, pl0 [32768], pl1 [32768]
    int pblk = g * 16 + (qt - 16);
    int srow = pblk * 64 + wave * 16 + l16;
    float* po = pscr + (size_t)p * (32768 * 64);
    float* pl = pscr + (size_t)2 * (32768 * 64) + (size_t)p * 32768;
#pragma unroll
    for (int nt2 = 0; nt2 < 4; ++nt2)
      *(f32x4*)&po[(size_t)srow * 64 + nt2 * 16 + quad * 4] = o_acc[nt2];
    if (lane < 16) pl[pblk * 64 + wave * 16 + lane] = lf;
  }
#undef STAGE_KV
}

// Combine split-K partials: O = (oA+oB)/(lA+lB) for q-rows >= 1024.
__global__ __launch_bounds__(256) void cmb_kernel(
    const float* __restrict__ pscr, short* __restrict__ O) {
  int gid = blockIdx.x * 256 + threadIdx.x;  // 0..2097151
  int srow = gid >> 6, dk = gid & 63;
  const float* po0 = pscr;
  const float* po1 = pscr + (size_t)32768 * 64;
  const float* pl0 = pscr + (size_t)2 * 32768 * 64;
  const float* pl1 = pl0 + 32768;
  float v = po0[gid] + po1[gid];
  float l = pl0[srow] + pl1[srow];
  int g = srow >> 10, rem = srow & 1023;
  int qt = 16 + (rem >> 6), row = rem & 63;
  int b = g >> 3, h = g & 7;
  int qrow = qt * 64 + row;
  O[((size_t)(b * SEQ + qrow)) * DM + h * DK + dk] = f2bf(v / l);
}

// ---------------------------------------------------------------------------
extern "C" void kernel_launch(void* const* d_in, const int* in_sizes, int n_in,
                              void* d_out, int out_size, void* d_ws, size_t ws_size,
                              hipStream_t stream) {
  const float* x   = (const float*)d_in[0];
  const float* Wq  = (const float*)d_in[1];
  const float* bq  = (const float*)d_in[2];
  const float* Wk  = (const float*)d_in[3];
  const float* bk  = (const float*)d_in[4];
  const float* Wv  = (const float*)d_in[5];
  const float* bv  = (const float*)d_in[6];
  const float* Wp  = (const float*)d_in[7];
  const float* bp  = (const float*)d_in[8];
  const float* W1  = (const float*)d_in[9];
  const float* b1  = (const float*)d_in[10];
  const float* W2  = (const float*)d_in[11];
  const float* b2  = (const float*)d_in[12];
  const float* g1  = (const float*)d_in[13];
  const float* be1 = (const float*)d_in[14];
  const float* g2  = (const float*)d_in[15];
  const float* be2 = (const float*)d_in[16];
  float* out = (float*)d_out;

  char* wsb = (char*)d_ws;
  const size_t SB = (size_t)BT * DM * 2;  // 8 MB
  short* h    = (short*)(wsb);
  short* q    = (short*)(wsb + SB);
  short* k    = (short*)(wsb + 2 * SB);
  short* vt   = (short*)(wsb + 3 * SB);
  short* o    = (short*)(wsb + 4 * SB);
  float* x2   = (float*)(wsb + 5 * SB);                       // 16 MB
  short* h2   = (short*)(wsb + 5 * SB + (size_t)BT * DM * 4);
  short* ff   = (short*)(wsb + 6 * SB + (size_t)BT * DM * 4); // 32 MB
  float* pscr = (float*)ff;   // split-K scratch (16.25 MB), dead before FF1
  short* wqkv = (short*)(wsb + 6 * SB + (size_t)BT * DM * 4 + (size_t)BT * FF * 2);
  short* wpt  = wqkv + 1536 * 512;
  short* w1t  = wpt + 512 * 512;
  short* w2t  = w1t + 2048 * 512;

  dim3 blk(256);

  wconv_kernel<<<dim3(768), blk, 0, stream>>>(Wq, Wk, Wv, Wp, W1, W2,
                                              wqkv, wpt, w1t, w2t);
  ln_kernel<<<BT, blk, 0, stream>>>(x, g1, be1, h);

  qkv_kernel<<<dim3(24, 64), blk, 0, stream>>>(h, wqkv, bq, bk, bv, q, k, vt);

  fattn_kernel<<<dim3(1536), blk, 0, stream>>>(q, k, vt, o, pscr);
  cmb_kernel<<<dim3(8192), blk, 0, stream>>>(pscr, o);

  mgemm64_kernel<<<dim3(8, 128), blk, 0, stream>>>(o, wpt, bp, x, x2, DM, DM, 0, 0);
  ln_kernel<<<BT, blk, 0, stream>>>(x2, g2, be2, h2);
  mgemm64_kernel<<<dim3(32, 128), blk, 0, stream>>>(h2, w1t, b1, nullptr, ff, FF, DM, 1, 1);
  mgemm64_kernel<<<dim3(8, 128), blk, 0, stream>>>(ff, w2t, b2, x2, out, DM, FF, 0, 0);
}